// Round 1
// baseline (2717.420 us; speedup 1.0000x reference)
//
#include <hip/hip_runtime.h>
#include <stdint.h>

#define NB 16
#define NN 1024
#define ND 256

typedef __bf16 bf16x8 __attribute__((ext_vector_type(8)));
typedef float f32x4 __attribute__((ext_vector_type(4)));

__device__ __forceinline__ unsigned short f2bf(float x){
  unsigned u = __builtin_bit_cast(unsigned, x);
  u += 0x7FFFu + ((u >> 16) & 1u);          // round-to-nearest-even
  return (unsigned short)(u >> 16);
}
__device__ __forceinline__ float bflo(unsigned u){ return __builtin_bit_cast(float, u << 16); }
__device__ __forceinline__ float bfhi(unsigned u){ return __builtin_bit_cast(float, u & 0xFFFF0000u); }

// ---------------- kernel 1: l2-normalize rows, cast to bf16 ----------------
// 32768 row-tasks (fA then fB), 1 wave per row, float4 loads.
__global__ __launch_bounds__(256) void norm_cast_kernel(
    const float* __restrict__ fA, const float* __restrict__ fB,
    unsigned short* __restrict__ Abf, unsigned short* __restrict__ Bbf)
{
  int task = blockIdx.x * 4 + (threadIdx.x >> 6);
  int lane = threadIdx.x & 63;
  const float* src = (task < NB*NN) ? fA : fB;
  unsigned short* dst = (task < NB*NN) ? Abf : Bbf;
  int row = (task < NB*NN) ? task : task - NB*NN;
  float4 x = ((const float4*)(src + (size_t)row*ND))[lane];
  float sq = x.x*x.x + x.y*x.y + x.z*x.z + x.w*x.w;
  #pragma unroll
  for (int off = 32; off > 0; off >>= 1) sq += __shfl_xor(sq, off);
  float s = rsqrtf(fmaxf(sq, 1e-12f));
  ushort4 o;
  o.x = f2bf(x.x*s); o.y = f2bf(x.y*s); o.z = f2bf(x.z*s); o.w = f2bf(x.w*s);
  ((ushort4*)(dst + (size_t)row*ND))[lane] = o;
}

// ---------------- kernel 2: S = A·B^T (bf16 MFMA), K = exp(5·clip(S)) ------
// 128x128 tile per 256-thread block, 2x2 wave grid, 16x16x32 bf16 MFMA.
#define LDK 40   // padded LDS tile row (elements) -> stride 80 B, balanced banks

__global__ __launch_bounds__(256) void gemm_exp_kernel(
    const unsigned short* __restrict__ Abf, const unsigned short* __restrict__ Bbf,
    float* __restrict__ S, unsigned short* __restrict__ Kg)
{
  __shared__ __align__(16) unsigned short As[128*LDK];
  __shared__ __align__(16) unsigned short Bs[128*LDK];
  const int b = blockIdx.z;
  const int mbase = blockIdx.y * 128;
  const int nbase = blockIdx.x * 128;
  const int t = threadIdx.x;
  const int lane = t & 63;
  const int wave = t >> 6;
  const int wm = wave >> 1, wn = wave & 1;
  const int quad = lane >> 4, l16 = lane & 15;

  const unsigned short* Ab = Abf + (size_t)b*NN*ND;
  const unsigned short* Bb = Bbf + (size_t)b*NN*ND;

  f32x4 acc[4][4];
  #pragma unroll
  for (int i=0;i<4;i++)
    #pragma unroll
    for (int j=0;j<4;j++) acc[i][j] = (f32x4){0.f,0.f,0.f,0.f};

  for (int k0 = 0; k0 < ND; k0 += 32){
    __syncthreads();                       // protect LDS from prior readers
    #pragma unroll
    for (int i=0;i<2;i++){
      int chunk = t + 256*i;               // 512 chunks of 16 B per matrix
      int row = chunk >> 2, seg = chunk & 3;
      *(uint4*)(&As[row*LDK + seg*8]) = *(const uint4*)(Ab + (size_t)(mbase+row)*ND + k0 + seg*8);
      *(uint4*)(&Bs[row*LDK + seg*8]) = *(const uint4*)(Bb + (size_t)(nbase+row)*ND + k0 + seg*8);
    }
    __syncthreads();
    bf16x8 af[4], bg[4];
    #pragma unroll
    for (int i=0;i<4;i++){
      // A-operand layout: m = lane&15, k = quad*8 + j  (m89-verified)
      af[i] = *(const bf16x8*)(&As[(wm*64 + i*16 + l16)*LDK + quad*8]);
      bg[i] = *(const bf16x8*)(&Bs[(wn*64 + i*16 + l16)*LDK + quad*8]);
    }
    #pragma unroll
    for (int i=0;i<4;i++)
      #pragma unroll
      for (int j=0;j<4;j++)
        acc[i][j] = __builtin_amdgcn_mfma_f32_16x16x32_bf16(af[i], bg[j], acc[i][j], 0, 0, 0);
  }

  // C/D layout: col = lane&15, row = quad*4 + reg  (m89-verified)
  float* Sb = S + (size_t)b*NN*NN;
  unsigned short* Kb = Kg + (size_t)b*NN*NN;
  #pragma unroll
  for (int i=0;i<4;i++){
    #pragma unroll
    for (int j=0;j<4;j++){
      int n = nbase + wn*64 + j*16 + l16;
      #pragma unroll
      for (int v=0;v<4;v++){
        int m = mbase + wm*64 + i*16 + quad*4 + v;
        float sv = acc[i][j][v];
        Sb[(size_t)m*NN + n] = sv;
        float sc = fminf(fmaxf(sv, -3.f), 3.f);   // clip (inactive: |S|<=1)
        Kb[(size_t)m*NN + n] = f2bf(__expf(5.f*sc));
      }
    }
  }
}

// ---------------- kernel 3: persistent Sinkhorn, K register-resident -------
// 256 blocks (1/CU) x 1024 threads. Block (b, rb) owns 64 rows of batch b.
// Each thread holds: row-slice K[r=t>>4][ci*64..+63] and col-slice K[0..63][t],
// both as 32 packed-bf16x2 VGPRs. One device barrier per iteration.
__global__ __launch_bounds__(1024) void sinkhorn_kernel(
    const unsigned short* __restrict__ Kg, float* __restrict__ P,
    float* __restrict__ pcol, unsigned* __restrict__ counter)
{
  __shared__ __align__(16) float v[NN];
  __shared__ __align__(16) float u[64];

  const int blk = blockIdx.x;
  const int b = blk >> 4;
  const int rb = blk & 15;
  const int t = threadIdx.x;
  const int r = t >> 4;
  const int ci = t & 15;

  const unsigned short* Kgb = Kg + ((size_t)(b*NN + rb*64))*NN;

  // column slice: rows 0..63 of column t, packed 2 rows per reg
  unsigned kcol[32];
  #pragma unroll
  for (int k=0;k<32;k++){
    unsigned lo = Kgb[(size_t)(2*k)*NN + t];
    unsigned hi = Kgb[(size_t)(2*k+1)*NN + t];
    kcol[k] = lo | (hi << 16);
  }
  // row slice: row r, cols ci*64 .. ci*64+63
  unsigned krow[32];
  {
    const uint4* rs = (const uint4*)(Kgb + (size_t)r*NN + ci*64);
    #pragma unroll
    for (int k=0;k<8;k++){
      uint4 w = rs[k];
      krow[4*k+0]=w.x; krow[4*k+1]=w.y; krow[4*k+2]=w.z; krow[4*k+3]=w.w;
    }
  }
  v[t] = 1.0f;                      // v0 = 1 (global normalize cancels)
  __syncthreads();

  const float4* v4 = (const float4*)v;
  const float4* u4 = (const float4*)u;
  float* pc0 = pcol + ((size_t)(b*16 + rb))*NN + t;
  const float* pr0 = pcol + (size_t)b*16*NN + t;

  for (int it = 0; it < 101; it++){     // 100 scan steps + 1 final step
    // phase A: u = 1/(K v)  (block-local rows)
    float rsum = 0.f;
    #pragma unroll
    for (int k=0;k<16;k++){
      float4 vv = v4[ci*16 + k];
      unsigned ka = krow[2*k], kb = krow[2*k+1];
      rsum += bflo(ka)*vv.x + bfhi(ka)*vv.y + bflo(kb)*vv.z + bfhi(kb)*vv.w;
    }
    rsum += __shfl_xor(rsum, 1);
    rsum += __shfl_xor(rsum, 2);
    rsum += __shfl_xor(rsum, 4);
    rsum += __shfl_xor(rsum, 8);
    if (ci == 0) u[r] = 1.0f / rsum;
    __syncthreads();
    // phase B: column partials over our 64 rows
    float csum = 0.f;
    #pragma unroll
    for (int k=0;k<16;k++){
      float4 uu = u4[k];
      unsigned ka = kcol[2*k], kb = kcol[2*k+1];
      csum += bflo(ka)*uu.x + bfhi(ka)*uu.y + bflo(kb)*uu.z + bfhi(kb)*uu.w;
    }
    int par = it & 1;                                  // double-buffered ws
    __hip_atomic_store(pc0 + (size_t)par*(16*16*NN), csum,
                       __ATOMIC_RELAXED, __HIP_MEMORY_SCOPE_AGENT);
    // device-wide barrier (1 block/CU guarantees co-residency)
    __syncthreads();
    if (t == 0){
      __hip_atomic_fetch_add(counter, 1u, __ATOMIC_ACQ_REL, __HIP_MEMORY_SCOPE_AGENT);
      unsigned tgt = 256u*(unsigned)(it+1);
      while (__hip_atomic_load(counter, __ATOMIC_ACQUIRE, __HIP_MEMORY_SCOPE_AGENT) < tgt)
        __builtin_amdgcn_s_sleep(2);
    }
    __syncthreads();
    // phase C: v = 1/(K^T u)  (redundant 16-way reduce; avoids 2nd barrier)
    float cs = 0.f;
    const float* base = pr0 + (size_t)par*(16*16*NN);
    #pragma unroll
    for (int p=0;p<16;p++)
      cs += __hip_atomic_load(base + (size_t)p*NN, __ATOMIC_RELAXED, __HIP_MEMORY_SCOPE_AGENT);
    v[t] = 1.0f / cs;
    __syncthreads();
  }

  // epilogue: P[row][t] = u[row]*K[row][t]*v[t]  (overwrites the K overlay;
  // safe: all K loads happened before barrier #1, this runs after #101)
  float* Pb = P + ((size_t)(b*NN + rb*64))*NN;
  float vt = v[t];
  #pragma unroll
  for (int k=0;k<16;k++){
    float4 uu = u4[k];
    unsigned ka = kcol[2*k], kb = kcol[2*k+1];
    Pb[(size_t)(4*k+0)*NN + t] = bflo(ka)*uu.x*vt;
    Pb[(size_t)(4*k+1)*NN + t] = bfhi(ka)*uu.y*vt;
    Pb[(size_t)(4*k+2)*NN + t] = bflo(kb)*uu.z*vt;
    Pb[(size_t)(4*k+3)*NN + t] = bfhi(kb)*uu.w*vt;
  }
}

extern "C" void kernel_launch(void* const* d_in, const int* in_sizes, int n_in,
                              void* d_out, int out_size, void* d_ws, size_t ws_size,
                              hipStream_t stream)
{
  const float* fA = (const float*)d_in[0];
  const float* fB = (const float*)d_in[1];
  float* Pout = (float*)d_out;                       // outputs: [P (16M f32) | Sij (16M f32)]
  float* Sout = Pout + (size_t)NB*NN*NN;
  unsigned short* Kg = (unsigned short*)d_out;       // bf16 K overlays P region (32 MB of 64 MB)

  unsigned short* Abf = (unsigned short*)d_ws;                          // 8 MB
  unsigned short* Bbf = Abf + (size_t)NB*NN*ND;                         // 8 MB
  float* pcol = (float*)((char*)d_ws + (size_t)16*1024*1024);           // 2 MB (double buffer)
  unsigned* counter = (unsigned*)((char*)d_ws + (size_t)16*1024*1024 + (size_t)2*16*16*NN*4);

  hipMemsetAsync(counter, 0, 4, stream);
  norm_cast_kernel<<<dim3(8192), dim3(256), 0, stream>>>(fA, fB, Abf, Bbf);
  gemm_exp_kernel<<<dim3(8,8,NB), dim3(256), 0, stream>>>(Abf, Bbf, Sout, Kg);
  sinkhorn_kernel<<<dim3(256), dim3(1024), 0, stream>>>(Kg, Pout, pcol, counter);
}

// Round 2
// 1793.436 us; speedup vs baseline: 1.5152x; 1.5152x over previous
//
#include <hip/hip_runtime.h>
#include <stdint.h>

#define NB 16
#define NN 1024
#define ND 256
#define PCSZ (16*16*NN)   // one parity's pcol buffer (floats)

typedef __bf16 bf16x8 __attribute__((ext_vector_type(8)));
typedef float f32x4 __attribute__((ext_vector_type(4)));

__device__ __forceinline__ unsigned short f2bf(float x){
  unsigned u = __builtin_bit_cast(unsigned, x);
  u += 0x7FFFu + ((u >> 16) & 1u);          // round-to-nearest-even
  return (unsigned short)(u >> 16);
}
__device__ __forceinline__ float bflo(unsigned u){ return __builtin_bit_cast(float, u << 16); }
__device__ __forceinline__ float bfhi(unsigned u){ return __builtin_bit_cast(float, u & 0xFFFF0000u); }

// ---------------- kernel 1: l2-normalize rows, cast to bf16 ----------------
__global__ __launch_bounds__(256) void norm_cast_kernel(
    const float* __restrict__ fA, const float* __restrict__ fB,
    unsigned short* __restrict__ Abf, unsigned short* __restrict__ Bbf)
{
  int task = blockIdx.x * 4 + (threadIdx.x >> 6);
  int lane = threadIdx.x & 63;
  const float* src = (task < NB*NN) ? fA : fB;
  unsigned short* dst = (task < NB*NN) ? Abf : Bbf;
  int row = (task < NB*NN) ? task : task - NB*NN;
  float4 x = ((const float4*)(src + (size_t)row*ND))[lane];
  float sq = x.x*x.x + x.y*x.y + x.z*x.z + x.w*x.w;
  #pragma unroll
  for (int off = 32; off > 0; off >>= 1) sq += __shfl_xor(sq, off);
  float s = rsqrtf(fmaxf(sq, 1e-12f));
  ushort4 o;
  o.x = f2bf(x.x*s); o.y = f2bf(x.y*s); o.z = f2bf(x.z*s); o.w = f2bf(x.w*s);
  ((ushort4*)(dst + (size_t)row*ND))[lane] = o;
}

// ---------------- kernel 2: S = A·B^T (bf16 MFMA), K = exp(5·clip(S)) ------
#define LDK 40   // padded LDS tile row (elements)

__global__ __launch_bounds__(256) void gemm_exp_kernel(
    const unsigned short* __restrict__ Abf, const unsigned short* __restrict__ Bbf,
    float* __restrict__ S, unsigned short* __restrict__ Kg)
{
  __shared__ __align__(16) unsigned short As[128*LDK];
  __shared__ __align__(16) unsigned short Bs[128*LDK];
  const int b = blockIdx.z;
  const int mbase = blockIdx.y * 128;
  const int nbase = blockIdx.x * 128;
  const int t = threadIdx.x;
  const int lane = t & 63;
  const int wave = t >> 6;
  const int wm = wave >> 1, wn = wave & 1;
  const int quad = lane >> 4, l16 = lane & 15;

  const unsigned short* Ab = Abf + (size_t)b*NN*ND;
  const unsigned short* Bb = Bbf + (size_t)b*NN*ND;

  f32x4 acc[4][4];
  #pragma unroll
  for (int i=0;i<4;i++)
    #pragma unroll
    for (int j=0;j<4;j++) acc[i][j] = (f32x4){0.f,0.f,0.f,0.f};

  for (int k0 = 0; k0 < ND; k0 += 32){
    __syncthreads();
    #pragma unroll
    for (int i=0;i<2;i++){
      int chunk = t + 256*i;
      int row = chunk >> 2, seg = chunk & 3;
      *(uint4*)(&As[row*LDK + seg*8]) = *(const uint4*)(Ab + (size_t)(mbase+row)*ND + k0 + seg*8);
      *(uint4*)(&Bs[row*LDK + seg*8]) = *(const uint4*)(Bb + (size_t)(nbase+row)*ND + k0 + seg*8);
    }
    __syncthreads();
    bf16x8 af[4], bg[4];
    #pragma unroll
    for (int i=0;i<4;i++){
      af[i] = *(const bf16x8*)(&As[(wm*64 + i*16 + l16)*LDK + quad*8]);
      bg[i] = *(const bf16x8*)(&Bs[(wn*64 + i*16 + l16)*LDK + quad*8]);
    }
    #pragma unroll
    for (int i=0;i<4;i++)
      #pragma unroll
      for (int j=0;j<4;j++)
        acc[i][j] = __builtin_amdgcn_mfma_f32_16x16x32_bf16(af[i], bg[j], acc[i][j], 0, 0, 0);
  }

  float* Sb = S + (size_t)b*NN*NN;
  unsigned short* Kb = Kg + (size_t)b*NN*NN;
  #pragma unroll
  for (int i=0;i<4;i++){
    #pragma unroll
    for (int j=0;j<4;j++){
      int n = nbase + wn*64 + j*16 + l16;
      #pragma unroll
      for (int v=0;v<4;v++){
        int m = mbase + wm*64 + i*16 + quad*4 + v;
        float sv = acc[i][j][v];
        Sb[(size_t)m*NN + n] = sv;
        float sc = fminf(fmaxf(sv, -3.f), 3.f);
        Kb[(size_t)m*NN + n] = f2bf(__expf(5.f*sc));
      }
    }
  }
}

// ---------------- kernel 3: persistent Sinkhorn, K register-resident -------
// 256 blocks x 1024 threads; block (b, rb) owns rows [64rb, 64rb+64) of batch b.
// krow: thread (w=t>>6, l=t&63) holds K[l][64w..64w+63]  (row phase,
//       v read is wave-uniform -> LDS broadcast, zero conflicts)
// kcol: thread t holds K[0..63][t]                        (col phase + epilogue)
// Cross-block: only the 16 blocks of one batch exchange column partials,
// synced by a per-batch 16-way arrival counter (no device-wide barrier).
__global__ __launch_bounds__(1024) void sinkhorn_kernel(
    const unsigned short* __restrict__ Kg, float* __restrict__ P,
    float* __restrict__ pcol, unsigned* __restrict__ arrive)
{
  __shared__ __align__(16) float v[NN];
  __shared__ __align__(16) float part[NN];
  __shared__ __align__(16) float u[64];

  const int blk = blockIdx.x;
  const int b = blk >> 4;
  const int rb = blk & 15;
  const int t = threadIdx.x;
  const int w = t >> 6;      // wave id: column chunk for row phase
  const int l = t & 63;      // lane: row id for row phase

  const unsigned short* Kgb = Kg + ((size_t)(b*NN + rb*64))*NN;

  // column slice: rows 0..63 of column t, packed 2 rows per u32
  unsigned kcol[32];
  #pragma unroll
  for (int k=0;k<32;k++){
    unsigned lo = Kgb[(size_t)(2*k)*NN + t];
    unsigned hi = Kgb[(size_t)(2*k+1)*NN + t];
    kcol[k] = lo | (hi << 16);
  }
  // row slice: row l, cols w*64 .. w*64+63
  unsigned krow[32];
  {
    const uint4* rs = (const uint4*)(Kgb + (size_t)l*NN + w*64);
    #pragma unroll
    for (int k=0;k<8;k++){
      uint4 q4 = rs[k];
      krow[4*k+0]=q4.x; krow[4*k+1]=q4.y; krow[4*k+2]=q4.z; krow[4*k+3]=q4.w;
    }
  }
  v[t] = 1.0f;                      // v0 = 1 (global normalize cancels)
  __syncthreads();

  const float4* v4 = (const float4*)v;
  const float4* u4 = (const float4*)u;
  float* pc0 = pcol + ((size_t)(b*16 + rb))*NN + t;
  const float* pr0 = pcol + (size_t)b*16*NN + t;
  unsigned* arr = arrive + b*64;    // 256 B per-batch spacing

  for (int it = 0; it < 101; it++){     // 100 scan steps + 1 final step
    // phase A: u = 1/(K v). Wave w covers cols [64w,64w+64) of row l.
    float rsum = 0.f;
    #pragma unroll
    for (int k=0;k<16;k++){
      float4 vv = v4[w*16 + k];         // wave-uniform -> broadcast, no conflict
      unsigned ka = krow[2*k], kb = krow[2*k+1];
      rsum += bflo(ka)*vv.x + bfhi(ka)*vv.y + bflo(kb)*vv.z + bfhi(kb)*vv.w;
    }
    part[w*64 + l] = rsum;              // bank = l%32 -> 2-way, free
    __syncthreads();
    if (t < 64){
      float s = 0.f;
      #pragma unroll
      for (int q=0;q<16;q++) s += part[q*64 + t];
      u[t] = 1.0f / s;
    }
    __syncthreads();
    // phase B: column partials over our 64 rows (u reads broadcast)
    float csum = 0.f;
    #pragma unroll
    for (int k=0;k<16;k++){
      float4 uu = u4[k];
      unsigned ka = kcol[2*k], kb = kcol[2*k+1];
      csum += bflo(ka)*uu.x + bfhi(ka)*uu.y + bflo(kb)*uu.z + bfhi(kb)*uu.w;
    }
    int par = it & 1;                                  // double-buffered ws
    __hip_atomic_store(pc0 + (size_t)par*PCSZ, csum,
                       __ATOMIC_RELAXED, __HIP_MEMORY_SCOPE_AGENT);
    // per-batch 16-block sync (blocks of one batch only)
    __syncthreads();
    if (t == 0){
      __hip_atomic_fetch_add(arr, 1u, __ATOMIC_ACQ_REL, __HIP_MEMORY_SCOPE_AGENT);
      unsigned tgt = 16u*(unsigned)(it+1);
      while (__hip_atomic_load(arr, __ATOMIC_ACQUIRE, __HIP_MEMORY_SCOPE_AGENT) < tgt)
        __builtin_amdgcn_s_sleep(1);
    }
    __syncthreads();
    // phase C: v = 1/(K^T u) from 16 per-block partials
    float cs = 0.f;
    const float* base = pr0 + (size_t)par*PCSZ;
    #pragma unroll
    for (int p=0;p<16;p++)
      cs += __hip_atomic_load(base + (size_t)p*NN, __ATOMIC_RELAXED, __HIP_MEMORY_SCOPE_AGENT);
    v[t] = 1.0f / cs;
    __syncthreads();
  }

  // epilogue: P[row][t] = u[row]*K[row][t]*v[t]  (overwrites K overlay; safe)
  float* Pb = P + ((size_t)(b*NN + rb*64))*NN;
  float vt = v[t];
  #pragma unroll
  for (int k=0;k<16;k++){
    float4 uu = u4[k];
    unsigned ka = kcol[2*k], kb = kcol[2*k+1];
    Pb[(size_t)(4*k+0)*NN + t] = bflo(ka)*uu.x*vt;
    Pb[(size_t)(4*k+1)*NN + t] = bfhi(ka)*uu.y*vt;
    Pb[(size_t)(4*k+2)*NN + t] = bflo(kb)*uu.z*vt;
    Pb[(size_t)(4*k+3)*NN + t] = bfhi(kb)*uu.w*vt;
  }
}

extern "C" void kernel_launch(void* const* d_in, const int* in_sizes, int n_in,
                              void* d_out, int out_size, void* d_ws, size_t ws_size,
                              hipStream_t stream)
{
  const float* fA = (const float*)d_in[0];
  const float* fB = (const float*)d_in[1];
  float* Pout = (float*)d_out;                       // outputs: [P | Sij]
  float* Sout = Pout + (size_t)NB*NN*NN;
  unsigned short* Kg = (unsigned short*)d_out;       // bf16 K overlays P region

  unsigned short* Abf = (unsigned short*)d_ws;                          // 8 MB
  unsigned short* Bbf = Abf + (size_t)NB*NN*ND;                         // 8 MB
  float* pcol = (float*)((char*)d_ws + (size_t)16*1024*1024);           // 2 MB
  unsigned* arrive = (unsigned*)((char*)d_ws + (size_t)16*1024*1024 + (size_t)2*PCSZ*4);

  hipMemsetAsync(arrive, 0, 64*4*NB, stream);
  norm_cast_kernel<<<dim3(8192), dim3(256), 0, stream>>>(fA, fB, Abf, Bbf);
  gemm_exp_kernel<<<dim3(8,8,NB), dim3(256), 0, stream>>>(Abf, Bbf, Sout, Kg);
  sinkhorn_kernel<<<dim3(256), dim3(1024), 0, stream>>>(Kg, Pout, pcol, arrive);
}